// Round 14
// baseline (147.690 us; speedup 1.0000x reference)
//
#include <hip/hip_runtime.h>
#include <hip/hip_bf16.h>
#include <stdint.h>

#define TT 16384
#define DD 768
#define EE 8
#define FF 469
#define FP 512
#define NCHUNK (TT / 64)
#define MAXT 71   // sum ceil(Ne/256) <= 64 + 7

typedef __attribute__((ext_vector_type(8))) short s16x8;
typedef __attribute__((ext_vector_type(4))) float f32x4;

__device__ __forceinline__ ushort f2bf(float f) {
  uint32_t u = __builtin_bit_cast(uint32_t, f);
  u += 0x7fffu + ((u >> 16) & 1u);
  return (ushort)(u >> 16);
}

__device__ __forceinline__ void gload16(const void* g, void* l) {
  __builtin_amdgcn_global_load_lds((const __attribute__((address_space(1))) unsigned int*)g,
                                   (__attribute__((address_space(3))) unsigned int*)l,
                                   16, 0, 0);
}

// ---------------- fused prep: gate (+x->bf16, histogram) | weight conversions ----------------
#define N12 (EE * 2 * FP * (DD / 4))
#define N3  (EE * DD * (FP / 4))
__global__ __launch_bounds__(256) void prep_kernel(
    const float* __restrict__ x, const float* __restrict__ Wg,
    const float* __restrict__ bg, const float* __restrict__ W1,
    const float* __restrict__ W2, const float* __restrict__ W3,
    int* __restrict__ eidx, ushort* __restrict__ xbf, int* __restrict__ cnt,
    ushort* __restrict__ w12b, ushort* __restrict__ w3b) {
  int tid = threadIdx.x;
  if (blockIdx.x < TT / 4) {
    __shared__ float4 wgs[EE * DD / 4];
    for (int i = tid; i < EE * DD / 4; i += 256) wgs[i] = ((const float4*)Wg)[i];
    __syncthreads();

    int t = blockIdx.x * 4 + (tid >> 6);
    int lane = tid & 63;
    const float4* xr = (const float4*)(x + (size_t)t * DD);
    float4 xv[3];
#pragma unroll
    for (int k = 0; k < 3; ++k) xv[k] = xr[lane + 64 * k];

    float acc[EE];
#pragma unroll
    for (int e = 0; e < EE; ++e) acc[e] = 0.f;
#pragma unroll
    for (int k = 0; k < 3; ++k) {
#pragma unroll
      for (int e = 0; e < EE; ++e) {
        float4 w = wgs[e * 192 + lane + 64 * k];
        acc[e] += xv[k].x * w.x + xv[k].y * w.y + xv[k].z * w.z + xv[k].w * w.w;
      }
    }

    uint2* xd = (uint2*)(xbf + (size_t)t * DD);
#pragma unroll
    for (int k = 0; k < 3; ++k) {
      union { ushort u[4]; uint2 w; } p;
      p.u[0] = f2bf(xv[k].x); p.u[1] = f2bf(xv[k].y);
      p.u[2] = f2bf(xv[k].z); p.u[3] = f2bf(xv[k].w);
      xd[lane + 64 * k] = p.w;
    }

#pragma unroll
    for (int off = 32; off; off >>= 1) {
#pragma unroll
      for (int e = 0; e < EE; ++e) acc[e] += __shfl_down(acc[e], off);
    }
    if (lane == 0) {
      float best = acc[0] + bg[0];
      int bi = 0;
#pragma unroll
      for (int e = 1; e < EE; ++e) {
        float v = acc[e] + bg[e];
        if (v > best) { best = v; bi = e; }
      }
      eidx[t] = bi;
      atomicAdd(&cnt[bi * NCHUNK + (t >> 6)], 1);
    }
  } else {
    int vb = blockIdx.x - TT / 4;
    for (int i = vb * 256 + tid; i < N12 + N3; i += 2048 * 256) {
      if (i < N12) {
        int d4 = i % (DD / 4);
        int er = i / (DD / 4);
        int row = er & 1023;
        int e = er >> 10;
        int f = row >> 1;
        union { ushort u[4]; uint2 w; } p;
        if (f < FF) {
          const float* src = ((row & 1) ? W2 : W1) + ((size_t)e * FF + f) * DD;
          float4 v = ((const float4*)src)[d4];
          p.u[0] = f2bf(v.x); p.u[1] = f2bf(v.y); p.u[2] = f2bf(v.z); p.u[3] = f2bf(v.w);
        } else {
          p.w.x = 0u; p.w.y = 0u;
        }
        ((uint2*)w12b)[i] = p.w;
      } else {
        int j = i - N12;
        int f4 = (j % (FP / 4)) * 4;
        int ed = j / (FP / 4);
        union { ushort u[4]; uint2 w; } p;
#pragma unroll
        for (int q = 0; q < 4; ++q) {
          int f = f4 + q;
          p.u[q] = (f < FF) ? f2bf(W3[(size_t)ed * FF + f]) : (ushort)0;
        }
        ((uint2*)w3b)[(size_t)ed * (FP / 4) + (f4 >> 2)] = p.w;
      }
    }
  }
}

// ---------------- scan + 256-row tile table ----------------
__global__ void scan_kernel(const int* __restrict__ cnt, int* __restrict__ scanEx,
                            int* __restrict__ offs, int* __restrict__ tileE,
                            int* __restrict__ tileT0) {
  int e = threadIdx.x >> 6;
  int lane = threadIdx.x & 63;
  __shared__ int totals[EE];
  int carry = 0;
#pragma unroll
  for (int g = 0; g < NCHUNK / 64; ++g) {
    int v = cnt[e * NCHUNK + g * 64 + lane];
    int s = v;
#pragma unroll
    for (int d = 1; d < 64; d <<= 1) {
      int t = __shfl_up(s, d);
      if (lane >= d) s += t;
    }
    scanEx[e * NCHUNK + g * 64 + lane] = carry + s - v;
    carry += __shfl(s, 63);
  }
  if (lane == 0) totals[e] = carry;
  __syncthreads();
  if (threadIdx.x == 0) {
    int s = 0;
    for (int e2 = 0; e2 < EE; ++e2) { offs[e2] = s; s += totals[e2]; }
    offs[EE] = s;
    int idx = 0;
    for (int e2 = 0; e2 < EE; ++e2) {
      int nt = (totals[e2] + 255) >> 8;
      for (int j = 0; j < nt; ++j) { tileE[idx] = e2; tileT0[idx] = j << 8; ++idx; }
    }
    for (; idx < MAXT; ++idx) tileE[idx] = -1;
  }
}

// ---------------- scatter via in-chunk ballot rank ----------------
__global__ void scatter2_kernel(const int* __restrict__ eidx, const int* __restrict__ offs,
                                const int* __restrict__ scanEx, int* __restrict__ perm) {
  int c = blockIdx.x * 4 + (threadIdx.x >> 6);
  int lane = threadIdx.x & 63;
  int t = c * 64 + lane;
  int v = eidx[t];
  unsigned long long mym = 0;
#pragma unroll
  for (int e = 0; e < EE; ++e) {
    unsigned long long me = __ballot(v == e);
    if (v == e) mym = me;
  }
  int rank = __popcll(mym & ((1ULL << lane) - 1ULL));
  perm[offs[v] + scanEx[v * NCHUNK + c] + rank] = t;
}

// ---------------- grouped GEMM1: 256x256x64, 8 waves, 2-slot, quadrant phases ----------------
__global__ __launch_bounds__(512, 2) void ffn1_kernel(
    const ushort* __restrict__ xbf, const ushort* __restrict__ w12b,
    const int* __restrict__ perm, const int* __restrict__ offs,
    const int* __restrict__ tileE, const int* __restrict__ tileT0,
    ushort* __restrict__ hbf) {
  // nwg = 284 = 8*35+4; bijective XCD chunking (m204)
  int bid = blockIdx.x;
  int xcd = bid & 7, idx = bid >> 3;
  int L = (xcd < 4) ? xcd * 36 + idx : 144 + (xcd - 4) * 35 + idx;
  int ti = L >> 2, y = L & 3;
  int e = tileE[ti];
  if (e < 0) return;
  int tile0 = tileT0[ti];
  int gOff = offs[e];
  int Ne = offs[e + 1] - gOff;
  int n0 = y * 256;

  __shared__ __align__(16) short As[2][256 * 64];  // 64 KB
  __shared__ __align__(16) short Bs[2][256 * 64];  // 64 KB

  int tid = threadIdx.x;
  int w = tid >> 6, lane = tid & 63;
  int l8 = lane >> 3, lg = lane & 7;
  int gsrc = (lg ^ l8) * 8;  // swizzled source granule (elements), lane-constant

  // staging: wave w covers rows [w*32, w*32+32); gload j covers rows w*32+j*8+l8
  int last = gOff + Ne - 1;
  const ushort* aSrc[4];
  const ushort* bSrc[4];
#pragma unroll
  for (int j = 0; j < 4; ++j) {
    int row = w * 32 + j * 8 + l8;
    int tok = perm[min(gOff + tile0 + row, last)];
    aSrc[j] = xbf + (size_t)tok * DD + gsrc;
    bSrc[j] = w12b + ((size_t)(e << 10) + n0 + row) * DD + gsrc;
  }
  int sdst[4];
#pragma unroll
  for (int j = 0; j < 4; ++j) sdst[j] = (w * 32 + j * 8) * 64;

  // compute: wave (wr, wc): rows [wr*128,+128), cols [wc*64,+64)
  int wr = w >> 2, wc = w & 3;
  int lrow = lane & 15, kh = lane >> 4;
  int sw0 = (kh ^ (lrow & 7)) * 8;        // ks=0 granule byte-elems
  int sw1 = ((4 + kh) ^ (lrow & 7)) * 8;  // ks=1
  int aBase = (wr * 128 + lrow) * 64;
  int bBase = (wc * 64 + lrow) * 64;

  f32x4 acc[2][2][4][2];
#pragma unroll
  for (int mh = 0; mh < 2; ++mh)
#pragma unroll
    for (int nh = 0; nh < 2; ++nh)
#pragma unroll
      for (int mm = 0; mm < 4; ++mm)
#pragma unroll
        for (int nn = 0; nn < 2; ++nn)
          acc[mh][nh][mm][nn] = (f32x4){0.f, 0.f, 0.f, 0.f};

  // prologue: K-tile 0 -> slot 0 (8 gloads/wave)
#pragma unroll
  for (int j = 0; j < 4; ++j) gload16(aSrc[j], &As[0][sdst[j]]);
#pragma unroll
  for (int j = 0; j < 4; ++j) gload16(bSrc[j], &Bs[0][sdst[j]]);

  const int NT = DD / 64;  // 12
#pragma unroll
  for (int kt = 0; kt < NT; ++kt) {
    const int s = kt & 1;
    asm volatile("s_waitcnt vmcnt(0)" ::: "memory");  // slot s data landed (>=1 iter old)
    __builtin_amdgcn_s_barrier();                     // + all waves done with slot s^1
    __builtin_amdgcn_sched_barrier(0);
    const int ko = (kt + 1) * 64;
    const bool more = (kt + 1 < NT);

    s16x8 a[4][2], b[2][2][2];
    // ---- q0: stage A0,A1 | load all b + a(mh=0) | MFMA (0,0) ----
    if (more) {
      gload16(aSrc[0] + ko, &As[s ^ 1][sdst[0]]);
      gload16(aSrc[1] + ko, &As[s ^ 1][sdst[1]]);
    }
#pragma unroll
    for (int nh = 0; nh < 2; ++nh)
#pragma unroll
      for (int nn = 0; nn < 2; ++nn) {
        int rb = bBase + (nh * 32 + nn * 16) * 64;
        b[nh][nn][0] = *(const s16x8*)&Bs[s][rb + sw0];
        b[nh][nn][1] = *(const s16x8*)&Bs[s][rb + sw1];
      }
#pragma unroll
    for (int mm = 0; mm < 4; ++mm) {
      int ra = aBase + (mm * 16) * 64;
      a[mm][0] = *(const s16x8*)&As[s][ra + sw0];
      a[mm][1] = *(const s16x8*)&As[s][ra + sw1];
    }
    __builtin_amdgcn_s_setprio(1);
#pragma unroll
    for (int mm = 0; mm < 4; ++mm)
#pragma unroll
      for (int nn = 0; nn < 2; ++nn)
#pragma unroll
        for (int ks = 0; ks < 2; ++ks)
          acc[0][0][mm][nn] = __builtin_amdgcn_mfma_f32_16x16x32_bf16(a[mm][ks], b[0][nn][ks], acc[0][0][mm][nn], 0, 0, 0);
    __builtin_amdgcn_s_setprio(0);
    // ---- q1: stage A2,A3 | MFMA (0,1) ----
    if (more) {
      gload16(aSrc[2] + ko, &As[s ^ 1][sdst[2]]);
      gload16(aSrc[3] + ko, &As[s ^ 1][sdst[3]]);
    }
    __builtin_amdgcn_s_setprio(1);
#pragma unroll
    for (int mm = 0; mm < 4; ++mm)
#pragma unroll
      for (int nn = 0; nn < 2; ++nn)
#pragma unroll
        for (int ks = 0; ks < 2; ++ks)
          acc[0][1][mm][nn] = __builtin_amdgcn_mfma_f32_16x16x32_bf16(a[mm][ks], b[1][nn][ks], acc[0][1][mm][nn], 0, 0, 0);
    __builtin_amdgcn_s_setprio(0);
    // ---- q2: stage B0,B1 | load a(mh=1) | MFMA (1,0) ----
    if (more) {
      gload16(bSrc[0] + ko, &Bs[s ^ 1][sdst[0]]);
      gload16(bSrc[1] + ko, &Bs[s ^ 1][sdst[1]]);
    }
#pragma unroll
    for (int mm = 0; mm < 4; ++mm) {
      int ra = aBase + (64 + mm * 16) * 64;
      a[mm][0] = *(const s16x8*)&As[s][ra + sw0];
      a[mm][1] = *(const s16x8*)&As[s][ra + sw1];
    }
    __builtin_amdgcn_s_setprio(1);
#pragma unroll
    for (int mm = 0; mm < 4; ++mm)
#pragma unroll
      for (int nn = 0; nn < 2; ++nn)
#pragma unroll
        for (int ks = 0; ks < 2; ++ks)
          acc[1][0][mm][nn] = __builtin_amdgcn_mfma_f32_16x16x32_bf16(a[mm][ks], b[0][nn][ks], acc[1][0][mm][nn], 0, 0, 0);
    __builtin_amdgcn_s_setprio(0);
    // ---- q3: stage B2,B3 | MFMA (1,1) ----
    if (more) {
      gload16(bSrc[2] + ko, &Bs[s ^ 1][sdst[2]]);
      gload16(bSrc[3] + ko, &Bs[s ^ 1][sdst[3]]);
    }
    __builtin_amdgcn_s_setprio(1);
#pragma unroll
    for (int mm = 0; mm < 4; ++mm)
#pragma unroll
      for (int nn = 0; nn < 2; ++nn)
#pragma unroll
        for (int ks = 0; ks < 2; ++ks)
          acc[1][1][mm][nn] = __builtin_amdgcn_mfma_f32_16x16x32_bf16(a[mm][ks], b[1][nn][ks], acc[1][1][mm][nn], 0, 0, 0);
    __builtin_amdgcn_s_setprio(0);
  }

  // epilogue: interleaved cols 2f,2f+1 = u_f,v_f in adjacent lanes
#pragma unroll
  for (int mh = 0; mh < 2; ++mh)
#pragma unroll
    for (int nh = 0; nh < 2; ++nh)
#pragma unroll
      for (int mm = 0; mm < 4; ++mm)
#pragma unroll
        for (int nn = 0; nn < 2; ++nn) {
          int f = (n0 + wc * 64 + nh * 32 + nn * 16 + lrow) >> 1;
          int rbase = tile0 + wr * 128 + mh * 64 + mm * 16 + kh * 4;
#pragma unroll
          for (int r = 0; r < 4; ++r) {
            float val = acc[mh][nh][mm][nn][r];
            float par = __shfl_xor(val, 1);
            float u = (lane & 1) ? par : val;
            float vv = (lane & 1) ? val : par;
            float h = (u / (1.f + __expf(-u))) * vv;
            int gr = rbase + r;
            if (!(lane & 1) && gr < Ne)
              hbf[(size_t)(gOff + gr) * FP + f] = f2bf(h);
          }
        }
}

// ---------------- grouped GEMM2: 256x256x64, same structure, scatter to out ----------------
__global__ __launch_bounds__(512, 2) void ffn2_kernel(
    const ushort* __restrict__ hbf, const ushort* __restrict__ w3b,
    const int* __restrict__ perm, const int* __restrict__ offs,
    const int* __restrict__ tileE, const int* __restrict__ tileT0,
    float* __restrict__ out) {
  // nwg = 213 = 8*26+5
  int bid = blockIdx.x;
  int xcd = bid & 7, idx = bid >> 3;
  int L = (xcd < 5) ? xcd * 27 + idx : 135 + (xcd - 5) * 26 + idx;
  int ti = L / 3, y = L % 3;
  int e = tileE[ti];
  if (e < 0) return;
  int tile0 = tileT0[ti];
  int gOff = offs[e];
  int Ne = offs[e + 1] - gOff;
  int d0 = y * 256;

  __shared__ __align__(16) short As[2][256 * 64];
  __shared__ __align__(16) short Bs[2][256 * 64];

  int tid = threadIdx.x;
  int w = tid >> 6, lane = tid & 63;
  int l8 = lane >> 3, lg = lane & 7;
  int gsrc = (lg ^ l8) * 8;

  int last = gOff + Ne - 1;
  const ushort* aSrc[4];
  const ushort* bSrc[4];
#pragma unroll
  for (int j = 0; j < 4; ++j) {
    int row = w * 32 + j * 8 + l8;
    aSrc[j] = hbf + (size_t)min(gOff + tile0 + row, last) * FP + gsrc;
    bSrc[j] = w3b + ((size_t)e * DD + d0 + row) * FP + gsrc;
  }
  int sdst[4];
#pragma unroll
  for (int j = 0; j < 4; ++j) sdst[j] = (w * 32 + j * 8) * 64;

  int wr = w >> 2, wc = w & 3;
  int lrow = lane & 15, kh = lane >> 4;
  int sw0 = (kh ^ (lrow & 7)) * 8;
  int sw1 = ((4 + kh) ^ (lrow & 7)) * 8;
  int aBase = (wr * 128 + lrow) * 64;
  int bBase = (wc * 64 + lrow) * 64;

  f32x4 acc[2][2][4][2];
#pragma unroll
  for (int mh = 0; mh < 2; ++mh)
#pragma unroll
    for (int nh = 0; nh < 2; ++nh)
#pragma unroll
      for (int mm = 0; mm < 4; ++mm)
#pragma unroll
        for (int nn = 0; nn < 2; ++nn)
          acc[mh][nh][mm][nn] = (f32x4){0.f, 0.f, 0.f, 0.f};

#pragma unroll
  for (int j = 0; j < 4; ++j) gload16(aSrc[j], &As[0][sdst[j]]);
#pragma unroll
  for (int j = 0; j < 4; ++j) gload16(bSrc[j], &Bs[0][sdst[j]]);

  const int NT = FP / 64;  // 8
#pragma unroll
  for (int kt = 0; kt < NT; ++kt) {
    const int s = kt & 1;
    asm volatile("s_waitcnt vmcnt(0)" ::: "memory");
    __builtin_amdgcn_s_barrier();
    __builtin_amdgcn_sched_barrier(0);
    const int ko = (kt + 1) * 64;
    const bool more = (kt + 1 < NT);

    s16x8 a[4][2], b[2][2][2];
    if (more) {
      gload16(aSrc[0] + ko, &As[s ^ 1][sdst[0]]);
      gload16(aSrc[1] + ko, &As[s ^ 1][sdst[1]]);
    }
#pragma unroll
    for (int nh = 0; nh < 2; ++nh)
#pragma unroll
      for (int nn = 0; nn < 2; ++nn) {
        int rb = bBase + (nh * 32 + nn * 16) * 64;
        b[nh][nn][0] = *(const s16x8*)&Bs[s][rb + sw0];
        b[nh][nn][1] = *(const s16x8*)&Bs[s][rb + sw1];
      }
#pragma unroll
    for (int mm = 0; mm < 4; ++mm) {
      int ra = aBase + (mm * 16) * 64;
      a[mm][0] = *(const s16x8*)&As[s][ra + sw0];
      a[mm][1] = *(const s16x8*)&As[s][ra + sw1];
    }
    __builtin_amdgcn_s_setprio(1);
#pragma unroll
    for (int mm = 0; mm < 4; ++mm)
#pragma unroll
      for (int nn = 0; nn < 2; ++nn)
#pragma unroll
        for (int ks = 0; ks < 2; ++ks)
          acc[0][0][mm][nn] = __builtin_amdgcn_mfma_f32_16x16x32_bf16(a[mm][ks], b[0][nn][ks], acc[0][0][mm][nn], 0, 0, 0);
    __builtin_amdgcn_s_setprio(0);
    if (more) {
      gload16(aSrc[2] + ko, &As[s ^ 1][sdst[2]]);
      gload16(aSrc[3] + ko, &As[s ^ 1][sdst[3]]);
    }
    __builtin_amdgcn_s_setprio(1);
#pragma unroll
    for (int mm = 0; mm < 4; ++mm)
#pragma unroll
      for (int nn = 0; nn < 2; ++nn)
#pragma unroll
        for (int ks = 0; ks < 2; ++ks)
          acc[0][1][mm][nn] = __builtin_amdgcn_mfma_f32_16x16x32_bf16(a[mm][ks], b[1][nn][ks], acc[0][1][mm][nn], 0, 0, 0);
    __builtin_amdgcn_s_setprio(0);
    if (more) {
      gload16(bSrc[0] + ko, &Bs[s ^ 1][sdst[0]]);
      gload16(bSrc[1] + ko, &Bs[s ^ 1][sdst[1]]);
    }
#pragma unroll
    for (int mm = 0; mm < 4; ++mm) {
      int ra = aBase + (64 + mm * 16) * 64;
      a[mm][0] = *(const s16x8*)&As[s][ra + sw0];
      a[mm][1] = *(const s16x8*)&As[s][ra + sw1];
    }
    __builtin_amdgcn_s_setprio(1);
#pragma unroll
    for (int mm = 0; mm < 4; ++mm)
#pragma unroll
      for (int nn = 0; nn < 2; ++nn)
#pragma unroll
        for (int ks = 0; ks < 2; ++ks)
          acc[1][0][mm][nn] = __builtin_amdgcn_mfma_f32_16x16x32_bf16(a[mm][ks], b[0][nn][ks], acc[1][0][mm][nn], 0, 0, 0);
    __builtin_amdgcn_s_setprio(0);
    if (more) {
      gload16(bSrc[2] + ko, &Bs[s ^ 1][sdst[2]]);
      gload16(bSrc[3] + ko, &Bs[s ^ 1][sdst[3]]);
    }
    __builtin_amdgcn_s_setprio(1);
#pragma unroll
    for (int mm = 0; mm < 4; ++mm)
#pragma unroll
      for (int nn = 0; nn < 2; ++nn)
#pragma unroll
        for (int ks = 0; ks < 2; ++ks)
          acc[1][1][mm][nn] = __builtin_amdgcn_mfma_f32_16x16x32_bf16(a[mm][ks], b[1][nn][ks], acc[1][1][mm][nn], 0, 0, 0);
    __builtin_amdgcn_s_setprio(0);
  }

#pragma unroll
  for (int mh = 0; mh < 2; ++mh)
#pragma unroll
    for (int nh = 0; nh < 2; ++nh)
#pragma unroll
      for (int mm = 0; mm < 4; ++mm)
#pragma unroll
        for (int nn = 0; nn < 2; ++nn) {
          int col = d0 + wc * 64 + nh * 32 + nn * 16 + lrow;
          int rbase = tile0 + wr * 128 + mh * 64 + mm * 16 + kh * 4;
#pragma unroll
          for (int r = 0; r < 4; ++r) {
            int gr = rbase + r;
            if (gr < Ne) {
              int t = perm[gOff + gr];
              out[(size_t)t * DD + col] = acc[mh][nh][mm][nn][r];
            }
          }
        }
}

extern "C" void kernel_launch(void* const* d_in, const int* in_sizes, int n_in,
                              void* d_out, int out_size, void* d_ws, size_t ws_size,
                              hipStream_t stream) {
  const float* x = (const float*)d_in[0];
  const float* Wg = (const float*)d_in[1];
  const float* bg = (const float*)d_in[2];
  const float* W1 = (const float*)d_in[3];
  const float* W2 = (const float*)d_in[4];
  const float* W3 = (const float*)d_in[5];
  float* out = (float*)d_out;

  char* ws = (char*)d_ws;
  int* eidx = (int*)ws;
  int* perm = (int*)(ws + 65536);
  int* offs = (int*)(ws + 131072);
  int* cnt = (int*)(ws + 131072 + 128);
  int* scanEx = (int*)(ws + 131072 + 128 + 8192);
  int* tileE = (int*)(ws + 131072 + 128 + 16384);
  int* tileT0 = tileE + MAXT + 8;
  ushort* xbf = (ushort*)(ws + 262144);
  ushort* w12b = xbf + (size_t)TT * DD;
  ushort* w3b = w12b + (size_t)EE * 2 * FP * DD;
  ushort* hbf = w3b + (size_t)EE * DD * FP;

  hipMemsetAsync(cnt, 0, EE * NCHUNK * 4, stream);
  prep_kernel<<<TT / 4 + 2048, 256, 0, stream>>>(x, Wg, bg, W1, W2, W3,
                                                 eidx, xbf, cnt, w12b, w3b);
  scan_kernel<<<1, 512, 0, stream>>>(cnt, scanEx, offs, tileE, tileT0);
  scatter2_kernel<<<NCHUNK / 4, 256, 0, stream>>>(eidx, offs, scanEx, perm);
  ffn1_kernel<<<284, 512, 0, stream>>>(xbf, w12b, perm, offs, tileE, tileT0, hbf);
  ffn2_kernel<<<213, 512, 0, stream>>>(hbf, w3b, perm, offs, tileE, tileT0, out);
}

// Round 15
// 141.780 us; speedup vs baseline: 1.0417x; 1.0417x over previous
//
#include <hip/hip_runtime.h>
#include <hip/hip_bf16.h>
#include <stdint.h>

#define TT 16384
#define DD 768
#define EE 8
#define FF 469
#define FP 512
#define NCHUNK (TT / 64)
#define MAXT 71

typedef __attribute__((ext_vector_type(8))) short s16x8;
typedef __attribute__((ext_vector_type(4))) float f32x4;

__device__ __forceinline__ ushort f2bf(float f) {
  uint32_t u = __builtin_bit_cast(uint32_t, f);
  u += 0x7fffu + ((u >> 16) & 1u);
  return (ushort)(u >> 16);
}

__device__ __forceinline__ void gload16(const void* g, void* l) {
  __builtin_amdgcn_global_load_lds((const __attribute__((address_space(1))) unsigned int*)g,
                                   (__attribute__((address_space(3))) unsigned int*)l,
                                   16, 0, 0);
}

// ---------------- fused prep: gate (+x->bf16, histogram) | weight conversions ----------------
#define N12 (EE * 2 * FP * (DD / 4))
#define N3  (EE * DD * (FP / 4))
__global__ __launch_bounds__(256) void prep_kernel(
    const float* __restrict__ x, const float* __restrict__ Wg,
    const float* __restrict__ bg, const float* __restrict__ W1,
    const float* __restrict__ W2, const float* __restrict__ W3,
    int* __restrict__ eidx, ushort* __restrict__ xbf, int* __restrict__ cnt,
    ushort* __restrict__ w12b, ushort* __restrict__ w3b) {
  int tid = threadIdx.x;
  if (blockIdx.x < TT / 4) {
    __shared__ float4 wgs[EE * DD / 4];
    for (int i = tid; i < EE * DD / 4; i += 256) wgs[i] = ((const float4*)Wg)[i];
    __syncthreads();

    int t = blockIdx.x * 4 + (tid >> 6);
    int lane = tid & 63;
    const float4* xr = (const float4*)(x + (size_t)t * DD);
    float4 xv[3];
#pragma unroll
    for (int k = 0; k < 3; ++k) xv[k] = xr[lane + 64 * k];

    float acc[EE];
#pragma unroll
    for (int e = 0; e < EE; ++e) acc[e] = 0.f;
#pragma unroll
    for (int k = 0; k < 3; ++k) {
#pragma unroll
      for (int e = 0; e < EE; ++e) {
        float4 w = wgs[e * 192 + lane + 64 * k];
        acc[e] += xv[k].x * w.x + xv[k].y * w.y + xv[k].z * w.z + xv[k].w * w.w;
      }
    }

    uint2* xd = (uint2*)(xbf + (size_t)t * DD);
#pragma unroll
    for (int k = 0; k < 3; ++k) {
      union { ushort u[4]; uint2 w; } p;
      p.u[0] = f2bf(xv[k].x); p.u[1] = f2bf(xv[k].y);
      p.u[2] = f2bf(xv[k].z); p.u[3] = f2bf(xv[k].w);
      xd[lane + 64 * k] = p.w;
    }

#pragma unroll
    for (int off = 32; off; off >>= 1) {
#pragma unroll
      for (int e = 0; e < EE; ++e) acc[e] += __shfl_down(acc[e], off);
    }
    if (lane == 0) {
      float best = acc[0] + bg[0];
      int bi = 0;
#pragma unroll
      for (int e = 1; e < EE; ++e) {
        float v = acc[e] + bg[e];
        if (v > best) { best = v; bi = e; }
      }
      eidx[t] = bi;
      atomicAdd(&cnt[bi * NCHUNK + (t >> 6)], 1);
    }
  } else {
    int vb = blockIdx.x - TT / 4;
    for (int i = vb * 256 + tid; i < N12 + N3; i += 2048 * 256) {
      if (i < N12) {
        int d4 = i % (DD / 4);
        int er = i / (DD / 4);
        int row = er & 1023;
        int e = er >> 10;
        int f = row >> 1;
        union { ushort u[4]; uint2 w; } p;
        if (f < FF) {
          const float* src = ((row & 1) ? W2 : W1) + ((size_t)e * FF + f) * DD;
          float4 v = ((const float4*)src)[d4];
          p.u[0] = f2bf(v.x); p.u[1] = f2bf(v.y); p.u[2] = f2bf(v.z); p.u[3] = f2bf(v.w);
        } else {
          p.w.x = 0u; p.w.y = 0u;
        }
        ((uint2*)w12b)[i] = p.w;
      } else {
        int j = i - N12;
        int f4 = (j % (FP / 4)) * 4;
        int ed = j / (FP / 4);
        union { ushort u[4]; uint2 w; } p;
#pragma unroll
        for (int q = 0; q < 4; ++q) {
          int f = f4 + q;
          p.u[q] = (f < FF) ? f2bf(W3[(size_t)ed * FF + f]) : (ushort)0;
        }
        ((uint2*)w3b)[(size_t)ed * (FP / 4) + (f4 >> 2)] = p.w;
      }
    }
  }
}

// ---------------- scan + 256-row tile table ----------------
__global__ void scan_kernel(const int* __restrict__ cnt, int* __restrict__ scanEx,
                            int* __restrict__ offs, int* __restrict__ tileE,
                            int* __restrict__ tileT0) {
  int e = threadIdx.x >> 6;
  int lane = threadIdx.x & 63;
  __shared__ int totals[EE];
  int carry = 0;
#pragma unroll
  for (int g = 0; g < NCHUNK / 64; ++g) {
    int v = cnt[e * NCHUNK + g * 64 + lane];
    int s = v;
#pragma unroll
    for (int d = 1; d < 64; d <<= 1) {
      int t = __shfl_up(s, d);
      if (lane >= d) s += t;
    }
    scanEx[e * NCHUNK + g * 64 + lane] = carry + s - v;
    carry += __shfl(s, 63);
  }
  if (lane == 0) totals[e] = carry;
  __syncthreads();
  if (threadIdx.x == 0) {
    int s = 0;
    for (int e2 = 0; e2 < EE; ++e2) { offs[e2] = s; s += totals[e2]; }
    offs[EE] = s;
    int idx = 0;
    for (int e2 = 0; e2 < EE; ++e2) {
      int nt = (totals[e2] + 255) >> 8;
      for (int j = 0; j < nt; ++j) { tileE[idx] = e2; tileT0[idx] = j << 8; ++idx; }
    }
    for (; idx < MAXT; ++idx) tileE[idx] = -1;
  }
}

// ---------------- scatter via in-chunk ballot rank ----------------
__global__ void scatter2_kernel(const int* __restrict__ eidx, const int* __restrict__ offs,
                                const int* __restrict__ scanEx, int* __restrict__ perm) {
  int c = blockIdx.x * 4 + (threadIdx.x >> 6);
  int lane = threadIdx.x & 63;
  int t = c * 64 + lane;
  int v = eidx[t];
  unsigned long long mym = 0;
#pragma unroll
  for (int e = 0; e < EE; ++e) {
    unsigned long long me = __ballot(v == e);
    if (v == e) mym = me;
  }
  int rank = __popcll(mym & ((1ULL << lane) - 1ULL));
  perm[offs[v] + scanEx[v * NCHUNK + c] + rank] = t;
}

// ====== 256x256x64, 8 waves, half-tile pipeline, counted vmcnt(6) ======
// Phases per K-tile kt (slot s=kt&1):
//  q0: stage A(kt+1)h0 -> As[s^1]; vmcnt(6|0); barrier; ds_read a(mh0)+b(nh0); lgkm0; MFMA(0,0); barrier
//  q1: ds_read b(nh1); stage A(kt+1)h1; lgkm0; MFMA(0,1); barrier
//  q2: ds_read a(mh1); stage B(kt+2)h0 -> Bs[s]; lgkm0; MFMA(1,0); barrier
//  q3: stage B(kt+2)h1; MFMA(1,1); barrier

__global__ __launch_bounds__(512, 2) void ffn1_kernel(
    const ushort* __restrict__ xbf, const ushort* __restrict__ w12b,
    const int* __restrict__ perm, const int* __restrict__ offs,
    const int* __restrict__ tileE, const int* __restrict__ tileT0,
    ushort* __restrict__ hbf) {
  int bid = blockIdx.x;
  int xcd = bid & 7, idx = bid >> 3;
  int L = (xcd < 4) ? xcd * 36 + idx : 144 + (xcd - 4) * 35 + idx;
  int ti = L >> 2, y = L & 3;
  int e = tileE[ti];
  if (e < 0) return;
  int tile0 = tileT0[ti];
  int gOff = offs[e];
  int Ne = offs[e + 1] - gOff;
  int n0 = y * 256;

  __shared__ __align__(16) short As[2][2][128 * 64];  // [slot][half] 64 KB
  __shared__ __align__(16) short Bs[2][2][128 * 64];  // 64 KB

  int tid = threadIdx.x;
  int w = tid >> 6, lane = tid & 63;
  int gsrc = ((lane & 7) ^ ((lane >> 3) & 7)) * 8;  // pre-swizzled source granule
  int last = gOff + Ne - 1;

  // stage sources: [half][round]; local row = h*128 + r*64 + w*8 + (lane>>3)
  const ushort* aS[2][2];
  const ushort* bS[2][2];
#pragma unroll
  for (int h = 0; h < 2; ++h)
#pragma unroll
    for (int r = 0; r < 2; ++r) {
      int row = h * 128 + r * 64 + w * 8 + (lane >> 3);
      int tok = perm[min(gOff + tile0 + row, last)];
      aS[h][r] = xbf + (size_t)tok * DD + gsrc;
      bS[h][r] = w12b + ((size_t)(e << 10) + n0 + row) * DD + gsrc;
    }
  int ldst[2];  // element offset within [half] for round r (wave-uniform + HW lane*16)
  ldst[0] = w * 512;
  ldst[1] = 4096 + w * 512;

  int wr = w >> 2, wc = w & 3;
  int lrow = lane & 15, kh = lane >> 4;
  int sw[2] = {((kh) ^ (lrow & 7)) * 8, ((4 + kh) ^ (lrow & 7)) * 8};
  int bh = wc >> 1, brow0 = (wc & 1) * 64;

  f32x4 acc[2][2][4][2];
#pragma unroll
  for (int mh = 0; mh < 2; ++mh)
#pragma unroll
    for (int nh = 0; nh < 2; ++nh)
#pragma unroll
      for (int mm = 0; mm < 4; ++mm)
#pragma unroll
        for (int nn = 0; nn < 2; ++nn)
          acc[mh][nh][mm][nn] = (f32x4){0.f, 0.f, 0.f, 0.f};

  // prologue: A(0), B(0) -> slot0; B(1) -> slot1  (12 gloads)
#pragma unroll
  for (int h = 0; h < 2; ++h)
#pragma unroll
    for (int r = 0; r < 2; ++r) gload16(aS[h][r], &As[0][h][ldst[r]]);
#pragma unroll
  for (int h = 0; h < 2; ++h)
#pragma unroll
    for (int r = 0; r < 2; ++r) gload16(bS[h][r], &Bs[0][h][ldst[r]]);
#pragma unroll
  for (int h = 0; h < 2; ++h)
#pragma unroll
    for (int r = 0; r < 2; ++r) gload16(bS[h][r] + 64, &Bs[1][h][ldst[r]]);

  const int NT = DD / 64;  // 12
  s16x8 a[4][2], b[2][2][2];
#pragma unroll
  for (int kt = 0; kt < NT; ++kt) {
    const int s = kt & 1;
    const int kc = kt * 64;
    // ---- q0 ----
    if (kt + 1 < NT) {
      gload16(aS[0][0] + kc + 64, &As[s ^ 1][0][ldst[0]]);
      gload16(aS[0][1] + kc + 64, &As[s ^ 1][0][ldst[1]]);
      asm volatile("s_waitcnt vmcnt(6)" ::: "memory");
    } else {
      asm volatile("s_waitcnt vmcnt(0)" ::: "memory");
    }
    __builtin_amdgcn_s_barrier();
    __builtin_amdgcn_sched_barrier(0);
#pragma unroll
    for (int mm = 0; mm < 4; ++mm) {
      int ra = (mm * 16 + lrow) * 64;
      a[mm][0] = *(const s16x8*)&As[s][wr][ra + sw[0]];
      a[mm][1] = *(const s16x8*)&As[s][wr][ra + sw[1]];
    }
#pragma unroll
    for (int nn = 0; nn < 2; ++nn) {
      int rb = (brow0 + nn * 16 + lrow) * 64;
      b[0][nn][0] = *(const s16x8*)&Bs[s][bh][rb + sw[0]];
      b[0][nn][1] = *(const s16x8*)&Bs[s][bh][rb + sw[1]];
    }
    asm volatile("s_waitcnt lgkmcnt(0)" ::: "memory");
    __builtin_amdgcn_sched_barrier(0);
    __builtin_amdgcn_s_setprio(1);
#pragma unroll
    for (int mm = 0; mm < 4; ++mm)
#pragma unroll
      for (int nn = 0; nn < 2; ++nn)
#pragma unroll
        for (int ks = 0; ks < 2; ++ks)
          acc[0][0][mm][nn] = __builtin_amdgcn_mfma_f32_16x16x32_bf16(a[mm][ks], b[0][nn][ks], acc[0][0][mm][nn], 0, 0, 0);
    __builtin_amdgcn_s_setprio(0);
    __builtin_amdgcn_s_barrier();
    // ---- q1 ----
#pragma unroll
    for (int nn = 0; nn < 2; ++nn) {
      int rb = (brow0 + 32 + nn * 16 + lrow) * 64;
      b[1][nn][0] = *(const s16x8*)&Bs[s][bh][rb + sw[0]];
      b[1][nn][1] = *(const s16x8*)&Bs[s][bh][rb + sw[1]];
    }
    if (kt + 1 < NT) {
      gload16(aS[1][0] + kc + 64, &As[s ^ 1][1][ldst[0]]);
      gload16(aS[1][1] + kc + 64, &As[s ^ 1][1][ldst[1]]);
    }
    asm volatile("s_waitcnt lgkmcnt(0)" ::: "memory");
    __builtin_amdgcn_sched_barrier(0);
    __builtin_amdgcn_s_setprio(1);
#pragma unroll
    for (int mm = 0; mm < 4; ++mm)
#pragma unroll
      for (int nn = 0; nn < 2; ++nn)
#pragma unroll
        for (int ks = 0; ks < 2; ++ks)
          acc[0][1][mm][nn] = __builtin_amdgcn_mfma_f32_16x16x32_bf16(a[mm][ks], b[1][nn][ks], acc[0][1][mm][nn], 0, 0, 0);
    __builtin_amdgcn_s_setprio(0);
    __builtin_amdgcn_s_barrier();
    // ---- q2 ----
#pragma unroll
    for (int mm = 0; mm < 4; ++mm) {
      int ra = (64 + mm * 16 + lrow) * 64;
      a[mm][0] = *(const s16x8*)&As[s][wr][ra + sw[0]];
      a[mm][1] = *(const s16x8*)&As[s][wr][ra + sw[1]];
    }
    if (kt + 2 < NT) {
      gload16(bS[0][0] + kc + 128, &Bs[s][0][ldst[0]]);
      gload16(bS[0][1] + kc + 128, &Bs[s][0][ldst[1]]);
    }
    asm volatile("s_waitcnt lgkmcnt(0)" ::: "memory");
    __builtin_amdgcn_sched_barrier(0);
    __builtin_amdgcn_s_setprio(1);
#pragma unroll
    for (int mm = 0; mm < 4; ++mm)
#pragma unroll
      for (int nn = 0; nn < 2; ++nn)
#pragma unroll
        for (int ks = 0; ks < 2; ++ks)
          acc[1][0][mm][nn] = __builtin_amdgcn_mfma_f32_16x16x32_bf16(a[mm][ks], b[0][nn][ks], acc[1][0][mm][nn], 0, 0, 0);
    __builtin_amdgcn_s_setprio(0);
    __builtin_amdgcn_s_barrier();
    // ---- q3 ----
    if (kt + 2 < NT) {
      gload16(bS[1][0] + kc + 128, &Bs[s][1][ldst[0]]);
      gload16(bS[1][1] + kc + 128, &Bs[s][1][ldst[1]]);
    }
    __builtin_amdgcn_s_setprio(1);
#pragma unroll
    for (int mm = 0; mm < 4; ++mm)
#pragma unroll
      for (int nn = 0; nn < 2; ++nn)
#pragma unroll
        for (int ks = 0; ks < 2; ++ks)
          acc[1][1][mm][nn] = __builtin_amdgcn_mfma_f32_16x16x32_bf16(a[mm][ks], b[1][nn][ks], acc[1][1][mm][nn], 0, 0, 0);
    __builtin_amdgcn_s_setprio(0);
    __builtin_amdgcn_s_barrier();
  }

  // epilogue: interleaved cols 2f,2f+1 = u_f,v_f in adjacent lanes
#pragma unroll
  for (int mh = 0; mh < 2; ++mh)
#pragma unroll
    for (int nh = 0; nh < 2; ++nh)
#pragma unroll
      for (int mm = 0; mm < 4; ++mm)
#pragma unroll
        for (int nn = 0; nn < 2; ++nn) {
          int f = (n0 + wc * 64 + nh * 32 + nn * 16 + lrow) >> 1;
          int rbase = tile0 + wr * 128 + mh * 64 + mm * 16 + kh * 4;
#pragma unroll
          for (int r = 0; r < 4; ++r) {
            float val = acc[mh][nh][mm][nn][r];
            float par = __shfl_xor(val, 1);
            float u = (lane & 1) ? par : val;
            float vv = (lane & 1) ? val : par;
            float h = (u / (1.f + __expf(-u))) * vv;
            int gr = rbase + r;
            if (!(lane & 1) && gr < Ne)
              hbf[(size_t)(gOff + gr) * FP + f] = f2bf(h);
          }
        }
}

__global__ __launch_bounds__(512, 2) void ffn2_kernel(
    const ushort* __restrict__ hbf, const ushort* __restrict__ w3b,
    const int* __restrict__ perm, const int* __restrict__ offs,
    const int* __restrict__ tileE, const int* __restrict__ tileT0,
    float* __restrict__ out) {
  int bid = blockIdx.x;
  int xcd = bid & 7, idx = bid >> 3;
  int L = (xcd < 5) ? xcd * 27 + idx : 135 + (xcd - 5) * 26 + idx;
  int ti = L / 3, y = L % 3;
  int e = tileE[ti];
  if (e < 0) return;
  int tile0 = tileT0[ti];
  int gOff = offs[e];
  int Ne = offs[e + 1] - gOff;
  int d0 = y * 256;

  __shared__ __align__(16) short As[2][2][128 * 64];
  __shared__ __align__(16) short Bs[2][2][128 * 64];

  int tid = threadIdx.x;
  int w = tid >> 6, lane = tid & 63;
  int gsrc = ((lane & 7) ^ ((lane >> 3) & 7)) * 8;
  int last = gOff + Ne - 1;

  const ushort* aS[2][2];
  const ushort* bS[2][2];
#pragma unroll
  for (int h = 0; h < 2; ++h)
#pragma unroll
    for (int r = 0; r < 2; ++r) {
      int row = h * 128 + r * 64 + w * 8 + (lane >> 3);
      aS[h][r] = hbf + (size_t)min(gOff + tile0 + row, last) * FP + gsrc;
      bS[h][r] = w3b + ((size_t)e * DD + d0 + row) * FP + gsrc;
    }
  int ldst[2];
  ldst[0] = w * 512;
  ldst[1] = 4096 + w * 512;

  int wr = w >> 2, wc = w & 3;
  int lrow = lane & 15, kh = lane >> 4;
  int sw[2] = {((kh) ^ (lrow & 7)) * 8, ((4 + kh) ^ (lrow & 7)) * 8};
  int bh = wc >> 1, brow0 = (wc & 1) * 64;

  f32x4 acc[2][2][4][2];
#pragma unroll
  for (int mh = 0; mh < 2; ++mh)
#pragma unroll
    for (int nh = 0; nh < 2; ++nh)
#pragma unroll
      for (int mm = 0; mm < 4; ++mm)
#pragma unroll
        for (int nn = 0; nn < 2; ++nn)
          acc[mh][nh][mm][nn] = (f32x4){0.f, 0.f, 0.f, 0.f};

#pragma unroll
  for (int h = 0; h < 2; ++h)
#pragma unroll
    for (int r = 0; r < 2; ++r) gload16(aS[h][r], &As[0][h][ldst[r]]);
#pragma unroll
  for (int h = 0; h < 2; ++h)
#pragma unroll
    for (int r = 0; r < 2; ++r) gload16(bS[h][r], &Bs[0][h][ldst[r]]);
#pragma unroll
  for (int h = 0; h < 2; ++h)
#pragma unroll
    for (int r = 0; r < 2; ++r) gload16(bS[h][r] + 64, &Bs[1][h][ldst[r]]);

  const int NT = FP / 64;  // 8
  s16x8 a[4][2], b[2][2][2];
#pragma unroll
  for (int kt = 0; kt < NT; ++kt) {
    const int s = kt & 1;
    const int kc = kt * 64;
    if (kt + 1 < NT) {
      gload16(aS[0][0] + kc + 64, &As[s ^ 1][0][ldst[0]]);
      gload16(aS[0][1] + kc + 64, &As[s ^ 1][0][ldst[1]]);
      asm volatile("s_waitcnt vmcnt(6)" ::: "memory");
    } else {
      asm volatile("s_waitcnt vmcnt(0)" ::: "memory");
    }
    __builtin_amdgcn_s_barrier();
    __builtin_amdgcn_sched_barrier(0);
#pragma unroll
    for (int mm = 0; mm < 4; ++mm) {
      int ra = (mm * 16 + lrow) * 64;
      a[mm][0] = *(const s16x8*)&As[s][wr][ra + sw[0]];
      a[mm][1] = *(const s16x8*)&As[s][wr][ra + sw[1]];
    }
#pragma unroll
    for (int nn = 0; nn < 2; ++nn) {
      int rb = (brow0 + nn * 16 + lrow) * 64;
      b[0][nn][0] = *(const s16x8*)&Bs[s][bh][rb + sw[0]];
      b[0][nn][1] = *(const s16x8*)&Bs[s][bh][rb + sw[1]];
    }
    asm volatile("s_waitcnt lgkmcnt(0)" ::: "memory");
    __builtin_amdgcn_sched_barrier(0);
    __builtin_amdgcn_s_setprio(1);
#pragma unroll
    for (int mm = 0; mm < 4; ++mm)
#pragma unroll
      for (int nn = 0; nn < 2; ++nn)
#pragma unroll
        for (int ks = 0; ks < 2; ++ks)
          acc[0][0][mm][nn] = __builtin_amdgcn_mfma_f32_16x16x32_bf16(a[mm][ks], b[0][nn][ks], acc[0][0][mm][nn], 0, 0, 0);
    __builtin_amdgcn_s_setprio(0);
    __builtin_amdgcn_s_barrier();
#pragma unroll
    for (int nn = 0; nn < 2; ++nn) {
      int rb = (brow0 + 32 + nn * 16 + lrow) * 64;
      b[1][nn][0] = *(const s16x8*)&Bs[s][bh][rb + sw[0]];
      b[1][nn][1] = *(const s16x8*)&Bs[s][bh][rb + sw[1]];
    }
    if (kt + 1 < NT) {
      gload16(aS[1][0] + kc + 64, &As[s ^ 1][1][ldst[0]]);
      gload16(aS[1][1] + kc + 64, &As[s ^ 1][1][ldst[1]]);
    }
    asm volatile("s_waitcnt lgkmcnt(0)" ::: "memory");
    __builtin_amdgcn_sched_barrier(0);
    __builtin_amdgcn_s_setprio(1);
#pragma unroll
    for (int mm = 0; mm < 4; ++mm)
#pragma unroll
      for (int nn = 0; nn < 2; ++nn)
#pragma unroll
        for (int ks = 0; ks < 2; ++ks)
          acc[0][1][mm][nn] = __builtin_amdgcn_mfma_f32_16x16x32_bf16(a[mm][ks], b[1][nn][ks], acc[0][1][mm][nn], 0, 0, 0);
    __builtin_amdgcn_s_setprio(0);
    __builtin_amdgcn_s_barrier();
#pragma unroll
    for (int mm = 0; mm < 4; ++mm) {
      int ra = (64 + mm * 16 + lrow) * 64;
      a[mm][0] = *(const s16x8*)&As[s][wr][ra + sw[0]];
      a[mm][1] = *(const s16x8*)&As[s][wr][ra + sw[1]];
    }
    if (kt + 2 < NT) {
      gload16(bS[0][0] + kc + 128, &Bs[s][0][ldst[0]]);
      gload16(bS[0][1] + kc + 128, &Bs[s][0][ldst[1]]);
    }
    asm volatile("s_waitcnt lgkmcnt(0)" ::: "memory");
    __builtin_amdgcn_sched_barrier(0);
    __builtin_amdgcn_s_setprio(1);
#pragma unroll
    for (int mm = 0; mm < 4; ++mm)
#pragma unroll
      for (int nn = 0; nn < 2; ++nn)
#pragma unroll
        for (int ks = 0; ks < 2; ++ks)
          acc[1][0][mm][nn] = __builtin_amdgcn_mfma_f32_16x16x32_bf16(a[mm][ks], b[0][nn][ks], acc[1][0][mm][nn], 0, 0, 0);
    __builtin_amdgcn_s_setprio(0);
    __builtin_amdgcn_s_barrier();
    if (kt + 2 < NT) {
      gload16(bS[1][0] + kc + 128, &Bs[s][1][ldst[0]]);
      gload16(bS[1][1] + kc + 128, &Bs[s][1][ldst[1]]);
    }
    __builtin_amdgcn_s_setprio(1);
#pragma unroll
    for (int mm = 0; mm < 4; ++mm)
#pragma unroll
      for (int nn = 0; nn < 2; ++nn)
#pragma unroll
        for (int ks = 0; ks < 2; ++ks)
          acc[1][1][mm][nn] = __builtin_amdgcn_mfma_f32_16x16x32_bf16(a[mm][ks], b[1][nn][ks], acc[1][1][mm][nn], 0, 0, 0);
    __builtin_amdgcn_s_setprio(0);
    __builtin_amdgcn_s_barrier();
  }

#pragma unroll
  for (int mh = 0; mh < 2; ++mh)
#pragma unroll
    for (int nh = 0; nh < 2; ++nh)
#pragma unroll
      for (int mm = 0; mm < 4; ++mm)
#pragma unroll
        for (int nn = 0; nn < 2; ++nn) {
          int col = d0 + wc * 64 + nh * 32 + nn * 16 + lrow;
          int rbase = tile0 + wr * 128 + mh * 64 + mm * 16 + kh * 4;
#pragma unroll
          for (int r = 0; r < 4; ++r) {
            int gr = rbase + r;
            if (gr < Ne) {
              int t = perm[gOff + gr];
              out[(size_t)t * DD + col] = acc[mh][nh][mm][nn][r];
            }
          }
        }
}

extern "C" void kernel_launch(void* const* d_in, const int* in_sizes, int n_in,
                              void* d_out, int out_size, void* d_ws, size_t ws_size,
                              hipStream_t stream) {
  const float* x = (const float*)d_in[0];
  const float* Wg = (const float*)d_in[1];
  const float* bg = (const float*)d_in[2];
  const float* W1 = (const float*)d_in[3];
  const float* W2 = (const float*)d_in[4];
  const float* W3 = (const float*)d_in[5];
  float* out = (float*)d_out;

  char* ws = (char*)d_ws;
  int* eidx = (int*)ws;
  int* perm = (int*)(ws + 65536);
  int* offs = (int*)(ws + 131072);
  int* cnt = (int*)(ws + 131072 + 128);
  int* scanEx = (int*)(ws + 131072 + 128 + 8192);
  int* tileE = (int*)(ws + 131072 + 128 + 16384);
  int* tileT0 = tileE + MAXT + 8;
  ushort* xbf = (ushort*)(ws + 262144);
  ushort* w12b = xbf + (size_t)TT * DD;
  ushort* w3b = w12b + (size_t)EE * 2 * FP * DD;
  ushort* hbf = w3b + (size_t)EE * DD * FP;

  hipMemsetAsync(cnt, 0, EE * NCHUNK * 4, stream);
  prep_kernel<<<TT / 4 + 2048, 256, 0, stream>>>(x, Wg, bg, W1, W2, W3,
                                                 eidx, xbf, cnt, w12b, w3b);
  scan_kernel<<<1, 512, 0, stream>>>(cnt, scanEx, offs, tileE, tileT0);
  scatter2_kernel<<<NCHUNK / 4, 256, 0, stream>>>(eidx, offs, scanEx, perm);
  ffn1_kernel<<<284, 512, 0, stream>>>(xbf, w12b, perm, offs, tileE, tileT0, hbf);
  ffn2_kernel<<<213, 512, 0, stream>>>(hbf, w3b, perm, offs, tileE, tileT0, out);
}

// Round 16
// 120.616 us; speedup vs baseline: 1.2245x; 1.1755x over previous
//
#include <hip/hip_runtime.h>
#include <hip/hip_bf16.h>
#include <stdint.h>

#define TT 16384
#define DD 768
#define EE 8
#define FF 469
#define FP 512      // w12b interleaved row count / 2 (ffn1 N padding, unchanged)
#define FQ 480      // hbf / w3b column padding (ffn2 K), 469 -> 480
#define NCHUNK (TT / 64)
#define MAXTILES 136

typedef __attribute__((ext_vector_type(8))) short s16x8;
typedef __attribute__((ext_vector_type(4))) float f32x4;

__device__ __forceinline__ ushort f2bf(float f) {
  uint32_t u = __builtin_bit_cast(uint32_t, f);
  u += 0x7fffu + ((u >> 16) & 1u);
  return (ushort)(u >> 16);
}

__device__ __forceinline__ void gload16(const void* g, void* l) {
  __builtin_amdgcn_global_load_lds((const __attribute__((address_space(1))) unsigned int*)g,
                                   (__attribute__((address_space(3))) unsigned int*)l,
                                   16, 0, 0);
}

// ---------------- fused gating (fp32) + x->bf16 conversion + chunk histogram ----------------
__global__ __launch_bounds__(256) void gate_conv_kernel(
    const float* __restrict__ x, const float* __restrict__ Wg,
    const float* __restrict__ bg, int* __restrict__ eidx,
    ushort* __restrict__ xbf, int* __restrict__ cnt) {
  __shared__ float4 wgs[EE * DD / 4];  // 24 KB
  int tid = threadIdx.x;
  for (int i = tid; i < EE * DD / 4; i += 256) wgs[i] = ((const float4*)Wg)[i];
  __syncthreads();

  int t = blockIdx.x * 4 + (tid >> 6);
  int lane = tid & 63;
  const float4* xr = (const float4*)(x + (size_t)t * DD);
  float4 xv[3];
#pragma unroll
  for (int k = 0; k < 3; ++k) xv[k] = xr[lane + 64 * k];

  float acc[EE];
#pragma unroll
  for (int e = 0; e < EE; ++e) acc[e] = 0.f;
#pragma unroll
  for (int k = 0; k < 3; ++k) {
#pragma unroll
    for (int e = 0; e < EE; ++e) {
      float4 w = wgs[e * 192 + lane + 64 * k];
      acc[e] += xv[k].x * w.x + xv[k].y * w.y + xv[k].z * w.z + xv[k].w * w.w;
    }
  }

  uint2* xd = (uint2*)(xbf + (size_t)t * DD);
#pragma unroll
  for (int k = 0; k < 3; ++k) {
    union { ushort u[4]; uint2 w; } p;
    p.u[0] = f2bf(xv[k].x); p.u[1] = f2bf(xv[k].y);
    p.u[2] = f2bf(xv[k].z); p.u[3] = f2bf(xv[k].w);
    xd[lane + 64 * k] = p.w;
  }

#pragma unroll
  for (int off = 32; off; off >>= 1) {
#pragma unroll
    for (int e = 0; e < EE; ++e) acc[e] += __shfl_down(acc[e], off);
  }
  if (lane == 0) {
    float best = acc[0] + bg[0];
    int bi = 0;
#pragma unroll
    for (int e = 1; e < EE; ++e) {
      float v = acc[e] + bg[e];
      if (v > best) { best = v; bi = e; }
    }
    eidx[t] = bi;
    atomicAdd(&cnt[bi * NCHUNK + (t >> 6)], 1);  // 2048 counters, low contention
  }
}

// ---------------- wave-parallel exclusive scan + flat tile table ----------------
__global__ void scan_kernel(const int* __restrict__ cnt, int* __restrict__ scanEx,
                            int* __restrict__ offs, int* __restrict__ tileE,
                            int* __restrict__ tileT0) {
  int e = threadIdx.x >> 6;
  int lane = threadIdx.x & 63;
  __shared__ int totals[EE];
  int carry = 0;
#pragma unroll
  for (int g = 0; g < NCHUNK / 64; ++g) {
    int v = cnt[e * NCHUNK + g * 64 + lane];
    int s = v;
#pragma unroll
    for (int d = 1; d < 64; d <<= 1) {
      int t = __shfl_up(s, d);
      if (lane >= d) s += t;
    }
    scanEx[e * NCHUNK + g * 64 + lane] = carry + s - v;
    carry += __shfl(s, 63);
  }
  if (lane == 0) totals[e] = carry;
  __syncthreads();
  if (threadIdx.x == 0) {
    int s = 0;
    for (int e2 = 0; e2 < EE; ++e2) { offs[e2] = s; s += totals[e2]; }
    offs[EE] = s;
    int idx = 0;
    for (int e2 = 0; e2 < EE; ++e2) {
      int nt = (totals[e2] + 127) >> 7;
      for (int j = 0; j < nt; ++j) { tileE[idx] = e2; tileT0[idx] = j << 7; ++idx; }
    }
    for (; idx < MAXTILES; ++idx) tileE[idx] = -1;
  }
}

// ---------------- scatter via in-chunk ballot rank ----------------
__global__ void scatter2_kernel(const int* __restrict__ eidx, const int* __restrict__ offs,
                                const int* __restrict__ scanEx, int* __restrict__ perm) {
  int c = blockIdx.x * 4 + (threadIdx.x >> 6);
  int lane = threadIdx.x & 63;
  int t = c * 64 + lane;
  int v = eidx[t];
  unsigned long long mym = 0;
#pragma unroll
  for (int e = 0; e < EE; ++e) {
    unsigned long long me = __ballot(v == e);
    if (v == e) mym = me;
  }
  int rank = __popcll(mym & ((1ULL << lane) - 1ULL));
  perm[offs[v] + scanEx[v * NCHUNK + c] + rank] = t;
}

// ---------------- merged weight conversions: w12b (interleaved, 1024 rows) + w3b (480 cols) ----------------
#define N12 (EE * 2 * FP * (DD / 4))
#define N3  (EE * DD * (FQ / 4))
__global__ void convw_kernel(const float* __restrict__ W1, const float* __restrict__ W2,
                             const float* __restrict__ W3, ushort* __restrict__ w12b,
                             ushort* __restrict__ w3b) {
  for (int i = blockIdx.x * blockDim.x + threadIdx.x; i < N12 + N3;
       i += gridDim.x * blockDim.x) {
    if (i < N12) {
      int d4 = i % (DD / 4);
      int er = i / (DD / 4);
      int row = er & 1023;
      int e = er >> 10;
      int f = row >> 1;
      union { ushort u[4]; uint2 w; } p;
      if (f < FF) {
        const float* src = ((row & 1) ? W2 : W1) + ((size_t)e * FF + f) * DD;
        float4 v = ((const float4*)src)[d4];
        p.u[0] = f2bf(v.x); p.u[1] = f2bf(v.y); p.u[2] = f2bf(v.z); p.u[3] = f2bf(v.w);
      } else {
        p.w.x = 0u; p.w.y = 0u;
      }
      ((uint2*)w12b)[i] = p.w;
    } else {
      int j = i - N12;
      int f4 = (j % (FQ / 4)) * 4;
      int ed = j / (FQ / 4);  // e*DD + d
      union { ushort u[4]; uint2 w; } p;
#pragma unroll
      for (int q = 0; q < 4; ++q) {
        int f = f4 + q;
        p.u[q] = (f < FF) ? f2bf(W3[(size_t)ed * FF + f]) : (ushort)0;
      }
      ((uint2*)w3b)[(size_t)ed * (FQ / 4) + (f4 >> 2)] = p.w;
    }
  }
}

// ---------------- grouped GEMM1: 128x256 tile, 8 waves, 3-buf depth-2 counted vmcnt ----------------
__global__ __launch_bounds__(512, 4) void ffn1_kernel(
    const ushort* __restrict__ xbf, const ushort* __restrict__ w12b,
    const int* __restrict__ perm, const int* __restrict__ offs,
    const int* __restrict__ tileE, const int* __restrict__ tileT0,
    ushort* __restrict__ hbf) {
  // grid = 544 = 8*68; XCD-chunked: XCD k owns L in [68k, 68k+68)
  int bid = blockIdx.x;
  int L = (bid & 7) * 68 + (bid >> 3);
  int ti = L >> 2;
  int y = L & 3;
  int e = tileE[ti];
  if (e < 0) return;
  int tile0 = tileT0[ti];
  int gOff = offs[e];
  int Ne = offs[e + 1] - gOff;
  int n0 = y * 256;  // interleaved-col base (0..1023)

  __shared__ __align__(16) short As[3][128 * 32];  // 3 x 8 KB
  __shared__ __align__(16) short Bs[3][256 * 32];  // 3 x 16 KB

  int tid = threadIdx.x;
  int w = tid >> 6, lane = tid & 63;
  int lr = lane >> 2, lg = lane & 3;

  // A staging: wave w stages rows [w*16, w*16+16): 1 gload
  int ar = w * 16 + lr;
  int ag = lg ^ ((ar >> 1) & 3);
  int last = gOff + Ne - 1;
  int tok = perm[min(gOff + tile0 + ar, last)];
  const ushort* asrc = xbf + (size_t)tok * DD + ag * 8;
  int adst = (w * 16) * 32;

  // B staging: wave w stages rows [w*32, w*32+32): 2 gloads
  int br0 = w * 32 + lr, br1 = br0 + 16;
  int bg0 = lg ^ ((br0 >> 1) & 3);
  int bg1 = lg ^ ((br1 >> 1) & 3);
  const ushort* bsrc0 = w12b + ((size_t)(e << 10) + n0 + br0) * DD + bg0 * 8;
  const ushort* bsrc1 = w12b + ((size_t)(e << 10) + n0 + br1) * DD + bg1 * 8;
  int bdst0 = (w * 32) * 32;
  int bdst1 = bdst0 + 16 * 32;

  // compute: wave (wr, wc) owns rows wr*64..+64, cols wc*64..+64 (of 128x256)
  int wr = w >> 2, wc = w & 3;
  int lrow = lane & 15, kh = lane >> 4;
  int aoff[4], boff[4];
#pragma unroll
  for (int m = 0; m < 4; ++m) {
    int ra = wr * 64 + m * 16 + lrow;
    aoff[m] = ra * 32 + (kh ^ ((ra >> 1) & 3)) * 8;
    int rb = wc * 64 + m * 16 + lrow;
    boff[m] = rb * 32 + (kh ^ ((rb >> 1) & 3)) * 8;
  }

  f32x4 acc[4][4];
  f32x4 zero = {0.f, 0.f, 0.f, 0.f};
#pragma unroll
  for (int m = 0; m < 4; ++m)
#pragma unroll
    for (int n = 0; n < 4; ++n) acc[m][n] = zero;

  // prologue: T0 -> buf0, T1 -> buf1 (6 outstanding/wave)
#pragma unroll
  for (int t = 0; t < 2; ++t) {
    int k = t * 32;
    gload16(asrc + k, &As[t][adst]);
    gload16(bsrc0 + k, &Bs[t][bdst0]);
    gload16(bsrc1 + k, &Bs[t][bdst1]);
  }

  const int NT = DD / 32;  // 24
#pragma unroll
  for (int t = 0; t < NT; ++t) {
    const int cur = t % 3;
    if (t < NT - 1) asm volatile("s_waitcnt vmcnt(3)" ::: "memory");  // T(t+1)'s 3 in flight
    else            asm volatile("s_waitcnt vmcnt(0)" ::: "memory");
    __builtin_amdgcn_s_barrier();
    __builtin_amdgcn_sched_barrier(0);
    if (t + 2 < NT) {
      const int nb = (t + 2) % 3;
      int k = (t + 2) * 32;
      gload16(asrc + k, &As[nb][adst]);
      gload16(bsrc0 + k, &Bs[nb][bdst0]);
      gload16(bsrc1 + k, &Bs[nb][bdst1]);
    }
    s16x8 af[4], bfr[4];
#pragma unroll
    for (int m = 0; m < 4; ++m) af[m] = *(const s16x8*)&As[cur][aoff[m]];
#pragma unroll
    for (int n = 0; n < 4; ++n) bfr[n] = *(const s16x8*)&Bs[cur][boff[n]];
    __builtin_amdgcn_s_setprio(1);
#pragma unroll
    for (int m = 0; m < 4; ++m)
#pragma unroll
      for (int n = 0; n < 4; ++n)
        acc[m][n] = __builtin_amdgcn_mfma_f32_16x16x32_bf16(af[m], bfr[n], acc[m][n], 0, 0, 0);
    __builtin_amdgcn_s_setprio(0);
  }

  // epilogue: interleaved cols 2f,2f+1 = u_f,v_f in adjacent lanes; hbf has FQ=480 cols
#pragma unroll
  for (int m = 0; m < 4; ++m) {
    int rbase = tile0 + wr * 64 + m * 16 + kh * 4;
#pragma unroll
    for (int n = 0; n < 4; ++n) {
      int f = (n0 + wc * 64 + n * 16 + lrow) >> 1;
#pragma unroll
      for (int r = 0; r < 4; ++r) {
        float val = acc[m][n][r];
        float par = __shfl_xor(val, 1);
        float u = (lane & 1) ? par : val;
        float vv = (lane & 1) ? val : par;
        float h = (u / (1.f + __expf(-u))) * vv;
        int gr = rbase + r;
        if (!(lane & 1) && gr < Ne && f < FQ)
          hbf[(size_t)(gOff + gr) * FQ + f] = f2bf(h);
      }
    }
  }
}

// ---------------- grouped GEMM2: 128x256 tile, 8 waves, K=480, 3-buf depth-2 counted vmcnt ----------------
__global__ __launch_bounds__(512, 4) void ffn2_kernel(
    const ushort* __restrict__ hbf, const ushort* __restrict__ w3b,
    const int* __restrict__ perm, const int* __restrict__ offs,
    const int* __restrict__ tileE, const int* __restrict__ tileT0,
    float* __restrict__ out) {
  // grid = 408 = 8*51; XCD k owns L in [51k, 51k+51)
  int bid = blockIdx.x;
  int L = (bid & 7) * 51 + (bid >> 3);
  int ti = L / 3;
  int y = L % 3;
  int e = tileE[ti];
  if (e < 0) return;
  int tile0 = tileT0[ti];
  int gOff = offs[e];
  int Ne = offs[e + 1] - gOff;
  int d0 = y * 256;

  __shared__ __align__(16) short As[3][128 * 32];
  __shared__ __align__(16) short Bs[3][256 * 32];

  int tid = threadIdx.x;
  int w = tid >> 6, lane = tid & 63;
  int lr = lane >> 2, lg = lane & 3;

  int ar = w * 16 + lr;
  int ag = lg ^ ((ar >> 1) & 3);
  int last = gOff + Ne - 1;
  const ushort* asrc = hbf + (size_t)min(gOff + tile0 + ar, last) * FQ + ag * 8;
  int adst = (w * 16) * 32;

  int br0 = w * 32 + lr, br1 = br0 + 16;
  int bg0 = lg ^ ((br0 >> 1) & 3);
  int bg1 = lg ^ ((br1 >> 1) & 3);
  const ushort* bsrc0 = w3b + ((size_t)e * DD + d0 + br0) * FQ + bg0 * 8;
  const ushort* bsrc1 = w3b + ((size_t)e * DD + d0 + br1) * FQ + bg1 * 8;
  int bdst0 = (w * 32) * 32;
  int bdst1 = bdst0 + 16 * 32;

  int wr = w >> 2, wc = w & 3;
  int lrow = lane & 15, kh = lane >> 4;
  int aoff[4], boff[4];
#pragma unroll
  for (int m = 0; m < 4; ++m) {
    int ra = wr * 64 + m * 16 + lrow;
    aoff[m] = ra * 32 + (kh ^ ((ra >> 1) & 3)) * 8;
    int rb = wc * 64 + m * 16 + lrow;
    boff[m] = rb * 32 + (kh ^ ((rb >> 1) & 3)) * 8;
  }

  f32x4 acc[4][4];
  f32x4 zero = {0.f, 0.f, 0.f, 0.f};
#pragma unroll
  for (int m = 0; m < 4; ++m)
#pragma unroll
    for (int n = 0; n < 4; ++n) acc[m][n] = zero;

#pragma unroll
  for (int t = 0; t < 2; ++t) {
    int k = t * 32;
    gload16(asrc + k, &As[t][adst]);
    gload16(bsrc0 + k, &Bs[t][bdst0]);
    gload16(bsrc1 + k, &Bs[t][bdst1]);
  }

  const int NT = FQ / 32;  // 15
#pragma unroll
  for (int t = 0; t < NT; ++t) {
    const int cur = t % 3;
    if (t < NT - 1) asm volatile("s_waitcnt vmcnt(3)" ::: "memory");
    else            asm volatile("s_waitcnt vmcnt(0)" ::: "memory");
    __builtin_amdgcn_s_barrier();
    __builtin_amdgcn_sched_barrier(0);
    if (t + 2 < NT) {
      const int nb = (t + 2) % 3;
      int k = (t + 2) * 32;
      gload16(asrc + k, &As[nb][adst]);
      gload16(bsrc0 + k, &Bs[nb][bdst0]);
      gload16(bsrc1 + k, &Bs[nb][bdst1]);
    }
    s16x8 af[4], bfr[4];
#pragma unroll
    for (int m = 0; m < 4; ++m) af[m] = *(const s16x8*)&As[cur][aoff[m]];
#pragma unroll
    for (int n = 0; n < 4; ++n) bfr[n] = *(const s16x8*)&Bs[cur][boff[n]];
    __builtin_amdgcn_s_setprio(1);
#pragma unroll
    for (int m = 0; m < 4; ++m)
#pragma unroll
      for (int n = 0; n < 4; ++n)
        acc[m][n] = __builtin_amdgcn_mfma_f32_16x16x32_bf16(af[m], bfr[n], acc[m][n], 0, 0, 0);
    __builtin_amdgcn_s_setprio(0);
  }

#pragma unroll
  for (int m = 0; m < 4; ++m) {
#pragma unroll
    for (int r = 0; r < 4; ++r) {
      int gr = tile0 + wr * 64 + m * 16 + kh * 4 + r;
      if (gr < Ne) {
        int t = perm[gOff + gr];
        float* orow = out + (size_t)t * DD + d0 + wc * 64;
#pragma unroll
        for (int n = 0; n < 4; ++n) orow[n * 16 + lrow] = acc[m][n][r];
      }
    }
  }
}

extern "C" void kernel_launch(void* const* d_in, const int* in_sizes, int n_in,
                              void* d_out, int out_size, void* d_ws, size_t ws_size,
                              hipStream_t stream) {
  const float* x = (const float*)d_in[0];
  const float* Wg = (const float*)d_in[1];
  const float* bg = (const float*)d_in[2];
  const float* W1 = (const float*)d_in[3];
  const float* W2 = (const float*)d_in[4];
  const float* W3 = (const float*)d_in[5];
  float* out = (float*)d_out;

  char* ws = (char*)d_ws;
  int* eidx = (int*)ws;
  int* perm = (int*)(ws + 65536);
  int* offs = (int*)(ws + 131072);
  int* cnt = (int*)(ws + 131072 + 128);
  int* scanEx = (int*)(ws + 131072 + 128 + 8192);
  int* tileE = (int*)(ws + 131072 + 128 + 16384);
  int* tileT0 = tileE + MAXTILES + 8;
  ushort* xbf = (ushort*)(ws + 262144);
  ushort* w12b = xbf + (size_t)TT * DD;
  ushort* w3b = w12b + (size_t)EE * 2 * FP * DD;
  ushort* hbf = w3b + (size_t)EE * DD * FQ;
  // ws usage: 256KB + 2*(16384*768 + 8*1024*768 + 8*768*480 + 16384*480) B  ≈ 76 MB

  hipMemsetAsync(cnt, 0, EE * NCHUNK * 4, stream);
  gate_conv_kernel<<<TT / 4, 256, 0, stream>>>(x, Wg, bg, eidx, xbf, cnt);
  convw_kernel<<<2048, 256, 0, stream>>>(W1, W2, W3, w12b, w3b);
  scan_kernel<<<1, 512, 0, stream>>>(cnt, scanEx, offs, tileE, tileT0);
  scatter2_kernel<<<NCHUNK / 4, 256, 0, stream>>>(eidx, offs, scanEx, perm);
  ffn1_kernel<<<8 * 68, 512, 0, stream>>>(xbf, w12b, perm, offs, tileE, tileT0, hbf);
  ffn2_kernel<<<8 * 51, 512, 0, stream>>>(hbf, w3b, perm, offs, tileE, tileT0, out);
}

// Round 17
// 119.368 us; speedup vs baseline: 1.2373x; 1.0105x over previous
//
#include <hip/hip_runtime.h>
#include <hip/hip_bf16.h>
#include <stdint.h>

#define TT 16384
#define DD 768
#define EE 8
#define FF 469
#define FP 512      // w12b interleaved row count / 2 (ffn1 N padding)
#define FQ 480      // hbf / w3b column padding (ffn2 K)
#define NCHUNK (TT / 64)
#define MAXTILES 136

typedef __attribute__((ext_vector_type(8))) short s16x8;
typedef __attribute__((ext_vector_type(4))) float f32x4;

__device__ __forceinline__ ushort f2bf(float f) {
  uint32_t u = __builtin_bit_cast(uint32_t, f);
  u += 0x7fffu + ((u >> 16) & 1u);
  return (ushort)(u >> 16);
}

__device__ __forceinline__ void gload16(const void* g, void* l) {
  __builtin_amdgcn_global_load_lds((const __attribute__((address_space(1))) unsigned int*)g,
                                   (__attribute__((address_space(3))) unsigned int*)l,
                                   16, 0, 0);
}

// ---------------- fused gating (fp32) + x->bf16 conversion + chunk histogram ----------------
__global__ __launch_bounds__(256) void gate_conv_kernel(
    const float* __restrict__ x, const float* __restrict__ Wg,
    const float* __restrict__ bg, int* __restrict__ eidx,
    ushort* __restrict__ xbf, int* __restrict__ cnt) {
  __shared__ float4 wgs[EE * DD / 4];  // 24 KB
  int tid = threadIdx.x;
  for (int i = tid; i < EE * DD / 4; i += 256) wgs[i] = ((const float4*)Wg)[i];
  __syncthreads();

  int t = blockIdx.x * 4 + (tid >> 6);
  int lane = tid & 63;
  const float4* xr = (const float4*)(x + (size_t)t * DD);
  float4 xv[3];
#pragma unroll
  for (int k = 0; k < 3; ++k) xv[k] = xr[lane + 64 * k];

  float acc[EE];
#pragma unroll
  for (int e = 0; e < EE; ++e) acc[e] = 0.f;
#pragma unroll
  for (int k = 0; k < 3; ++k) {
#pragma unroll
    for (int e = 0; e < EE; ++e) {
      float4 w = wgs[e * 192 + lane + 64 * k];
      acc[e] += xv[k].x * w.x + xv[k].y * w.y + xv[k].z * w.z + xv[k].w * w.w;
    }
  }

  uint2* xd = (uint2*)(xbf + (size_t)t * DD);
#pragma unroll
  for (int k = 0; k < 3; ++k) {
    union { ushort u[4]; uint2 w; } p;
    p.u[0] = f2bf(xv[k].x); p.u[1] = f2bf(xv[k].y);
    p.u[2] = f2bf(xv[k].z); p.u[3] = f2bf(xv[k].w);
    xd[lane + 64 * k] = p.w;
  }

#pragma unroll
  for (int off = 32; off; off >>= 1) {
#pragma unroll
    for (int e = 0; e < EE; ++e) acc[e] += __shfl_down(acc[e], off);
  }
  if (lane == 0) {
    float best = acc[0] + bg[0];
    int bi = 0;
#pragma unroll
    for (int e = 1; e < EE; ++e) {
      float v = acc[e] + bg[e];
      if (v > best) { best = v; bi = e; }
    }
    eidx[t] = bi;
    atomicAdd(&cnt[bi * NCHUNK + (t >> 6)], 1);  // 2048 counters, low contention
  }
}

// ---------------- wave-parallel exclusive scan + flat tile table ----------------
__global__ void scan_kernel(const int* __restrict__ cnt, int* __restrict__ scanEx,
                            int* __restrict__ offs, int* __restrict__ tileE,
                            int* __restrict__ tileT0) {
  int e = threadIdx.x >> 6;
  int lane = threadIdx.x & 63;
  __shared__ int totals[EE];
  int carry = 0;
#pragma unroll
  for (int g = 0; g < NCHUNK / 64; ++g) {
    int v = cnt[e * NCHUNK + g * 64 + lane];
    int s = v;
#pragma unroll
    for (int d = 1; d < 64; d <<= 1) {
      int t = __shfl_up(s, d);
      if (lane >= d) s += t;
    }
    scanEx[e * NCHUNK + g * 64 + lane] = carry + s - v;
    carry += __shfl(s, 63);
  }
  if (lane == 0) totals[e] = carry;
  __syncthreads();
  if (threadIdx.x == 0) {
    int s = 0;
    for (int e2 = 0; e2 < EE; ++e2) { offs[e2] = s; s += totals[e2]; }
    offs[EE] = s;
    int idx = 0;
    for (int e2 = 0; e2 < EE; ++e2) {
      int nt = (totals[e2] + 127) >> 7;
      for (int j = 0; j < nt; ++j) { tileE[idx] = e2; tileT0[idx] = j << 7; ++idx; }
    }
    for (; idx < MAXTILES; ++idx) tileE[idx] = -1;
  }
}

// ---------------- scatter via in-chunk ballot rank ----------------
__global__ void scatter2_kernel(const int* __restrict__ eidx, const int* __restrict__ offs,
                                const int* __restrict__ scanEx, int* __restrict__ perm) {
  int c = blockIdx.x * 4 + (threadIdx.x >> 6);
  int lane = threadIdx.x & 63;
  int t = c * 64 + lane;
  int v = eidx[t];
  unsigned long long mym = 0;
#pragma unroll
  for (int e = 0; e < EE; ++e) {
    unsigned long long me = __ballot(v == e);
    if (v == e) mym = me;
  }
  int rank = __popcll(mym & ((1ULL << lane) - 1ULL));
  perm[offs[v] + scanEx[v * NCHUNK + c] + rank] = t;
}

// ---------------- merged weight conversions: w12b (interleaved) + w3b (480 cols) ----------------
#define N12 (EE * 2 * FP * (DD / 4))
#define N3  (EE * DD * (FQ / 4))
__global__ void convw_kernel(const float* __restrict__ W1, const float* __restrict__ W2,
                             const float* __restrict__ W3, ushort* __restrict__ w12b,
                             ushort* __restrict__ w3b) {
  for (int i = blockIdx.x * blockDim.x + threadIdx.x; i < N12 + N3;
       i += gridDim.x * blockDim.x) {
    if (i < N12) {
      int d4 = i % (DD / 4);
      int er = i / (DD / 4);
      int row = er & 1023;
      int e = er >> 10;
      int f = row >> 1;
      union { ushort u[4]; uint2 w; } p;
      if (f < FF) {
        const float* src = ((row & 1) ? W2 : W1) + ((size_t)e * FF + f) * DD;
        float4 v = ((const float4*)src)[d4];
        p.u[0] = f2bf(v.x); p.u[1] = f2bf(v.y); p.u[2] = f2bf(v.z); p.u[3] = f2bf(v.w);
      } else {
        p.w.x = 0u; p.w.y = 0u;
      }
      ((uint2*)w12b)[i] = p.w;
    } else {
      int j = i - N12;
      int f4 = (j % (FQ / 4)) * 4;
      int ed = j / (FQ / 4);  // e*DD + d
      union { ushort u[4]; uint2 w; } p;
#pragma unroll
      for (int q = 0; q < 4; ++q) {
        int f = f4 + q;
        p.u[q] = (f < FF) ? f2bf(W3[(size_t)ed * FF + f]) : (ushort)0;
      }
      ((uint2*)w3b)[(size_t)ed * (FQ / 4) + (f4 >> 2)] = p.w;
    }
  }
}

// ---------------- grouped GEMM1: 128x256 tile, 8 waves, 3-buf depth-2 counted vmcnt ----------------
__global__ __launch_bounds__(512, 4) void ffn1_kernel(
    const ushort* __restrict__ xbf, const ushort* __restrict__ w12b,
    const int* __restrict__ perm, const int* __restrict__ offs,
    const int* __restrict__ tileE, const int* __restrict__ tileT0,
    ushort* __restrict__ hbf) {
  // grid = 544 = 8*68; XCD-chunked: XCD k owns L in [68k, 68k+68)
  int bid = blockIdx.x;
  int L = (bid & 7) * 68 + (bid >> 3);
  int ti = L >> 2;
  int y = L & 3;
  int e = tileE[ti];
  if (e < 0) return;
  int tile0 = tileT0[ti];
  int gOff = offs[e];
  int Ne = offs[e + 1] - gOff;
  int n0 = y * 256;  // interleaved-col base (0..1023)

  __shared__ __align__(16) short As[3][128 * 32];  // 3 x 8 KB
  __shared__ __align__(16) short Bs[3][256 * 32];  // 3 x 16 KB

  int tid = threadIdx.x;
  int w = tid >> 6, lane = tid & 63;
  int lr = lane >> 2, lg = lane & 3;

  // A staging: wave w stages rows [w*16, w*16+16): 1 gload
  int ar = w * 16 + lr;
  int ag = lg ^ ((ar >> 1) & 3);
  int last = gOff + Ne - 1;
  int tok = perm[min(gOff + tile0 + ar, last)];
  const ushort* asrc = xbf + (size_t)tok * DD + ag * 8;
  int adst = (w * 16) * 32;

  // B staging: wave w stages rows [w*32, w*32+32): 2 gloads
  int br0 = w * 32 + lr, br1 = br0 + 16;
  int bg0 = lg ^ ((br0 >> 1) & 3);
  int bg1 = lg ^ ((br1 >> 1) & 3);
  const ushort* bsrc0 = w12b + ((size_t)(e << 10) + n0 + br0) * DD + bg0 * 8;
  const ushort* bsrc1 = w12b + ((size_t)(e << 10) + n0 + br1) * DD + bg1 * 8;
  int bdst0 = (w * 32) * 32;
  int bdst1 = bdst0 + 16 * 32;

  // compute: wave (wr, wc) owns rows wr*64..+64, cols wc*64..+64 (of 128x256)
  int wr = w >> 2, wc = w & 3;
  int lrow = lane & 15, kh = lane >> 4;
  int aoff[4], boff[4];
#pragma unroll
  for (int m = 0; m < 4; ++m) {
    int ra = wr * 64 + m * 16 + lrow;
    aoff[m] = ra * 32 + (kh ^ ((ra >> 1) & 3)) * 8;
    int rb = wc * 64 + m * 16 + lrow;
    boff[m] = rb * 32 + (kh ^ ((rb >> 1) & 3)) * 8;
  }

  f32x4 acc[4][4];
  f32x4 zero = {0.f, 0.f, 0.f, 0.f};
#pragma unroll
  for (int m = 0; m < 4; ++m)
#pragma unroll
    for (int n = 0; n < 4; ++n) acc[m][n] = zero;

  // prologue: T0 -> buf0, T1 -> buf1 (6 outstanding/wave)
#pragma unroll
  for (int t = 0; t < 2; ++t) {
    int k = t * 32;
    gload16(asrc + k, &As[t][adst]);
    gload16(bsrc0 + k, &Bs[t][bdst0]);
    gload16(bsrc1 + k, &Bs[t][bdst1]);
  }

  const int NT = DD / 32;  // 24
#pragma unroll
  for (int t = 0; t < NT; ++t) {
    const int cur = t % 3;
    if (t < NT - 1) asm volatile("s_waitcnt vmcnt(3)" ::: "memory");  // T(t+1)'s 3 in flight
    else            asm volatile("s_waitcnt vmcnt(0)" ::: "memory");
    __builtin_amdgcn_s_barrier();
    __builtin_amdgcn_sched_barrier(0);
    if (t + 2 < NT) {
      const int nb = (t + 2) % 3;
      int k = (t + 2) * 32;
      gload16(asrc + k, &As[nb][adst]);
      gload16(bsrc0 + k, &Bs[nb][bdst0]);
      gload16(bsrc1 + k, &Bs[nb][bdst1]);
    }
    s16x8 af[4], bfr[4];
#pragma unroll
    for (int m = 0; m < 4; ++m) af[m] = *(const s16x8*)&As[cur][aoff[m]];
#pragma unroll
    for (int n = 0; n < 4; ++n) bfr[n] = *(const s16x8*)&Bs[cur][boff[n]];
#pragma unroll
    for (int m = 0; m < 4; ++m)
#pragma unroll
      for (int n = 0; n < 4; ++n)
        acc[m][n] = __builtin_amdgcn_mfma_f32_16x16x32_bf16(af[m], bfr[n], acc[m][n], 0, 0, 0);
  }

  // epilogue: interleaved cols 2f,2f+1 = u_f,v_f in adjacent lanes; hbf has FQ=480 cols
#pragma unroll
  for (int m = 0; m < 4; ++m) {
    int rbase = tile0 + wr * 64 + m * 16 + kh * 4;
#pragma unroll
    for (int n = 0; n < 4; ++n) {
      int f = (n0 + wc * 64 + n * 16 + lrow) >> 1;
#pragma unroll
      for (int r = 0; r < 4; ++r) {
        float val = acc[m][n][r];
        float par = __shfl_xor(val, 1);
        float u = (lane & 1) ? par : val;
        float vv = (lane & 1) ? val : par;
        float h = (u / (1.f + __expf(-u))) * vv;
        int gr = rbase + r;
        if (!(lane & 1) && gr < Ne && f < FQ)
          hbf[(size_t)(gOff + gr) * FQ + f] = f2bf(h);
      }
    }
  }
}

// ---------------- grouped GEMM2: 128x256 tile, 8 waves, K=480, 3-buf depth-2 counted vmcnt ----------------
__global__ __launch_bounds__(512, 4) void ffn2_kernel(
    const ushort* __restrict__ hbf, const ushort* __restrict__ w3b,
    const int* __restrict__ perm, const int* __restrict__ offs,
    const int* __restrict__ tileE, const int* __restrict__ tileT0,
    float* __restrict__ out) {
  // grid = 408 = 8*51; XCD k owns L in [51k, 51k+51)
  int bid = blockIdx.x;
  int L = (bid & 7) * 51 + (bid >> 3);
  int ti = L / 3;
  int y = L % 3;
  int e = tileE[ti];
  if (e < 0) return;
  int tile0 = tileT0[ti];
  int gOff = offs[e];
  int Ne = offs[e + 1] - gOff;
  int d0 = y * 256;

  __shared__ __align__(16) short As[3][128 * 32];
  __shared__ __align__(16) short Bs[3][256 * 32];

  int tid = threadIdx.x;
  int w = tid >> 6, lane = tid & 63;
  int lr = lane >> 2, lg = lane & 3;

  int ar = w * 16 + lr;
  int ag = lg ^ ((ar >> 1) & 3);
  int last = gOff + Ne - 1;
  const ushort* asrc = hbf + (size_t)min(gOff + tile0 + ar, last) * FQ + ag * 8;
  int adst = (w * 16) * 32;

  int br0 = w * 32 + lr, br1 = br0 + 16;
  int bg0 = lg ^ ((br0 >> 1) & 3);
  int bg1 = lg ^ ((br1 >> 1) & 3);
  const ushort* bsrc0 = w3b + ((size_t)e * DD + d0 + br0) * FQ + bg0 * 8;
  const ushort* bsrc1 = w3b + ((size_t)e * DD + d0 + br1) * FQ + bg1 * 8;
  int bdst0 = (w * 32) * 32;
  int bdst1 = bdst0 + 16 * 32;

  int wr = w >> 2, wc = w & 3;
  int lrow = lane & 15, kh = lane >> 4;
  int aoff[4], boff[4];
#pragma unroll
  for (int m = 0; m < 4; ++m) {
    int ra = wr * 64 + m * 16 + lrow;
    aoff[m] = ra * 32 + (kh ^ ((ra >> 1) & 3)) * 8;
    int rb = wc * 64 + m * 16 + lrow;
    boff[m] = rb * 32 + (kh ^ ((rb >> 1) & 3)) * 8;
  }

  f32x4 acc[4][4];
  f32x4 zero = {0.f, 0.f, 0.f, 0.f};
#pragma unroll
  for (int m = 0; m < 4; ++m)
#pragma unroll
    for (int n = 0; n < 4; ++n) acc[m][n] = zero;

#pragma unroll
  for (int t = 0; t < 2; ++t) {
    int k = t * 32;
    gload16(asrc + k, &As[t][adst]);
    gload16(bsrc0 + k, &Bs[t][bdst0]);
    gload16(bsrc1 + k, &Bs[t][bdst1]);
  }

  const int NT = FQ / 32;  // 15
#pragma unroll
  for (int t = 0; t < NT; ++t) {
    const int cur = t % 3;
    if (t < NT - 1) asm volatile("s_waitcnt vmcnt(3)" ::: "memory");
    else            asm volatile("s_waitcnt vmcnt(0)" ::: "memory");
    __builtin_amdgcn_s_barrier();
    __builtin_amdgcn_sched_barrier(0);
    if (t + 2 < NT) {
      const int nb = (t + 2) % 3;
      int k = (t + 2) * 32;
      gload16(asrc + k, &As[nb][adst]);
      gload16(bsrc0 + k, &Bs[nb][bdst0]);
      gload16(bsrc1 + k, &Bs[nb][bdst1]);
    }
    s16x8 af[4], bfr[4];
#pragma unroll
    for (int m = 0; m < 4; ++m) af[m] = *(const s16x8*)&As[cur][aoff[m]];
#pragma unroll
    for (int n = 0; n < 4; ++n) bfr[n] = *(const s16x8*)&Bs[cur][boff[n]];
#pragma unroll
    for (int m = 0; m < 4; ++m)
#pragma unroll
      for (int n = 0; n < 4; ++n)
        acc[m][n] = __builtin_amdgcn_mfma_f32_16x16x32_bf16(af[m], bfr[n], acc[m][n], 0, 0, 0);
  }

#pragma unroll
  for (int m = 0; m < 4; ++m) {
#pragma unroll
    for (int r = 0; r < 4; ++r) {
      int gr = tile0 + wr * 64 + m * 16 + kh * 4 + r;
      if (gr < Ne) {
        int t = perm[gOff + gr];
        float* orow = out + (size_t)t * DD + d0 + wc * 64;
#pragma unroll
        for (int n = 0; n < 4; ++n) orow[n * 16 + lrow] = acc[m][n][r];
      }
    }
  }
}

extern "C" void kernel_launch(void* const* d_in, const int* in_sizes, int n_in,
                              void* d_out, int out_size, void* d_ws, size_t ws_size,
                              hipStream_t stream) {
  const float* x = (const float*)d_in[0];
  const float* Wg = (const float*)d_in[1];
  const float* bg = (const float*)d_in[2];
  const float* W1 = (const float*)d_in[3];
  const float* W2 = (const float*)d_in[4];
  const float* W3 = (const float*)d_in[5];
  float* out = (float*)d_out;

  char* ws = (char*)d_ws;
  int* eidx = (int*)ws;
  int* perm = (int*)(ws + 65536);
  int* offs = (int*)(ws + 131072);
  int* cnt = (int*)(ws + 131072 + 128);
  int* scanEx = (int*)(ws + 131072 + 128 + 8192);
  int* tileE = (int*)(ws + 131072 + 128 + 16384);
  int* tileT0 = tileE + MAXTILES + 8;
  ushort* xbf = (ushort*)(ws + 262144);
  ushort* w12b = xbf + (size_t)TT * DD;
  ushort* w3b = w12b + (size_t)EE * 2 * FP * DD;
  ushort* hbf = w3b + (size_t)EE * DD * FQ;

  hipMemsetAsync(cnt, 0, EE * NCHUNK * 4, stream);
  gate_conv_kernel<<<TT / 4, 256, 0, stream>>>(x, Wg, bg, eidx, xbf, cnt);
  convw_kernel<<<2048, 256, 0, stream>>>(W1, W2, W3, w12b, w3b);
  scan_kernel<<<1, 512, 0, stream>>>(cnt, scanEx, offs, tileE, tileT0);
  scatter2_kernel<<<NCHUNK / 4, 256, 0, stream>>>(eidx, offs, scanEx, perm);
  ffn1_kernel<<<8 * 68, 512, 0, stream>>>(xbf, w12b, perm, offs, tileE, tileT0, hbf);
  ffn2_kernel<<<8 * 51, 512, 0, stream>>>(hbf, w3b, perm, offs, tileE, tileT0, out);
}